// Round 16
// baseline (422.096 us; speedup 1.0000x reference)
//
#include <hip/hip_runtime.h>
#include <math.h>

#define N_NODES 50000
#define N_EDGES 800000
#define NPAD 50176
#define HSTR 224   // hbuf row stride in HALFS: 448 B = exactly 4 x 128B sectors per row fetch
#define RBIN 12544 // bins per histogram range (NPAD/4), 49 KB LDS as int
#define NCHK 32    // edge chunks; chunk = 25000 edges
// ecsbuf (NPAD+2 ints): after k_sum32, ecsbuf[1+d] = total in-degree count;
// after scans, ecsbuf[1+d] = start(d). Readers: start(n)=ecsbuf[n+1], end=ecsbuf[n+2].
// CSR build: ZERO global atomics (r7/r11). GEMM numerics (r12): A fp16,
// W split-fp16, f16 MFMA. r13/r15 lesson: source-level load batching gets
// UNDONE by LLVM's register-minimizing scheduler (VGPR stuck at 64, loads
// sunk to consumers, ~3 in flight). r16 fix: asm volatile liveness pins
// (guide rule #17) after the load cluster force all 14 B fragments resident
// before the MFMA cluster -> ~14 loads in flight, VGPR ~105 (<128 @ (256,4)).

typedef __attribute__((ext_vector_type(8))) _Float16 half8;
typedef __attribute__((ext_vector_type(4))) float f32x4;
typedef __attribute__((ext_vector_type(4))) _Float16 half4;
typedef __attribute__((ext_vector_type(2))) _Float16 half2_t;

// ---------------- helpers ----------------

__device__ __forceinline__ float fast_tanh(float x) {
    float e = __expf(2.0f * x);
    float r = __builtin_amdgcn_rcpf(e + 1.0f);
    return 1.0f - 2.0f * r;
}

__device__ __forceinline__ f32x4 mfma16f(half8 a, half8 b, f32x4 c) {
    return __builtin_amdgcn_mfma_f32_16x16x32_f16(a, b, c, 0, 0, 0);
}

// split W to fp16 hi + fp16 lo (hi = RNE(v); lo = RNE(v - hi))
__device__ __forceinline__ void wsplit_one(const float* __restrict__ W, int KIN, int LDA,
                                           _Float16* __restrict__ WT_hi,
                                           _Float16* __restrict__ WT_lo, int idx) {
    int n = idx / LDA;
    int k = idx - n * LDA;
    float v = (n < 220 && k < KIN) ? W[k * 220 + n] : 0.f;
    _Float16 hi = (_Float16)v;
    _Float16 lo = (_Float16)(v - (float)hi);
    WT_hi[idx] = hi;
    WT_lo[idx] = lo;
}

// ---------------- CSR build (zero global atomics) ----------------

// partitioned launch:
// [0,128)    dst rank job: rng = bx>>5, chk = bx&31 (4 ranges x 32 chunks)
// [128,256)  src hist job: same decomposition
// [256,284)  wsplit W0 | [284,480) W1 | [480,676) W2
__global__ void k_build(const int* __restrict__ ei, int* __restrict__ deg_part,
                        int* __restrict__ cnt_part, int* __restrict__ rank,
                        const float* __restrict__ W0, const float* __restrict__ W1,
                        const float* __restrict__ W2,
                        _Float16* __restrict__ wt0h, _Float16* __restrict__ wt0l,
                        _Float16* __restrict__ wt1h, _Float16* __restrict__ wt1l,
                        _Float16* __restrict__ wt2h, _Float16* __restrict__ wt2l) {
    __shared__ int hb[RBIN];   // 49 KB -> 3 blocks/CU
    int bx = blockIdx.x;
    if (bx < 128) {
        int rng = bx >> 5, chk = bx & 31;
        int lo = rng * RBIN;
        for (int i = threadIdx.x; i < RBIN; i += 256) hb[i] = 0;
        __syncthreads();
        int ebeg = chk * 25000, eend = ebeg + 25000;
        for (int e = ebeg + threadIdx.x; e < eend; e += 256) {
            int d = ei[N_EDGES + e];
            unsigned idx = (unsigned)(d - lo);
            if (idx < (unsigned)RBIN) {
                int lr = atomicAdd(&hb[idx], 1);     // LDS returning add
                rank[e] = (lr << 5) | chk;
            }
        }
        __syncthreads();
        for (int i = threadIdx.x; i < RBIN; i += 256)
            cnt_part[chk * NPAD + lo + i] = hb[i];
    } else if (bx < 256) {
        int b2 = bx - 128;
        int rng = b2 >> 5, chk = b2 & 31;
        int lo = rng * RBIN;
        for (int i = threadIdx.x; i < RBIN; i += 256) hb[i] = 0;
        __syncthreads();
        int ebeg = chk * 25000, eend = ebeg + 25000;
        for (int e = ebeg + threadIdx.x; e < eend; e += 256) {
            int s = ei[e];
            unsigned idx = (unsigned)(s - lo);
            if (idx < (unsigned)RBIN) atomicAdd(&hb[idx], 1);
        }
        __syncthreads();
        for (int i = threadIdx.x; i < RBIN; i += 256)
            deg_part[chk * NPAD + lo + i] = hb[i];
    } else if (bx < 284) {
        int idx = (bx - 256) * 256 + threadIdx.x;           // 224*32 = 7168
        if (idx < 224 * 32) wsplit_one(W0, 22, 32, wt0h, wt0l, idx);
    } else if (bx < 480) {
        int idx = (bx - 284) * 256 + threadIdx.x;           // 224*224 = 50176
        wsplit_one(W1, 220, 224, wt1h, wt1l, idx);
    } else {
        int idx = (bx - 480) * 256 + threadIdx.x;
        wsplit_one(W2, 220, 224, wt2h, wt2l, idx);
    }
}

// fold 32 chunk-partials: cnt_part -> in-place exclusive per-bin prefix,
// ecsbuf[1+d] = total in-degree, deg_out[d] = total out-degree.
__global__ void k_sum32(int* __restrict__ cnt_part, const int* __restrict__ deg_part,
                        int* __restrict__ ecsbuf, int* __restrict__ deg_out) {
    int d = blockIdx.x * 256 + threadIdx.x;
    if (d >= NPAD) return;
    int s = 0;
#pragma unroll
    for (int c = 0; c < NCHK; ++c) {
        int v = cnt_part[c * NPAD + d];
        cnt_part[c * NPAD + d] = s;
        s += v;
    }
    ecsbuf[1 + d] = s;
    if (d == 0) ecsbuf[0] = 0;
    int t = 0;
#pragma unroll
    for (int c = 0; c < NCHK; ++c) t += deg_part[c * NPAD + d];
    deg_out[d] = t;
}

__global__ void k_scan1(const int* __restrict__ in, int* __restrict__ out,
                        int* __restrict__ bsum, int n) {
    __shared__ int s[256];
    int i = blockIdx.x * 256 + threadIdx.x;
    int v = (i < n) ? in[i] : 0;
    s[threadIdx.x] = v;
    __syncthreads();
    for (int off = 1; off < 256; off <<= 1) {
        int t = (threadIdx.x >= off) ? s[threadIdx.x - off] : 0;
        __syncthreads();
        s[threadIdx.x] += t;
        __syncthreads();
    }
    if (i < n) out[i] = s[threadIdx.x] - v;   // exclusive
    if (threadIdx.x == 255 && bsum) bsum[blockIdx.x] = s[255];
}

__global__ void k_scan_mid(int* __restrict__ a, int n) {
    __shared__ int s[256];
    __shared__ int carry;
    if (threadIdx.x == 0) carry = 0;
    for (int base = 0; base < n; base += 256) {
        int i = base + threadIdx.x;
        int v = (i < n) ? a[i] : 0;
        s[threadIdx.x] = v;
        __syncthreads();
        for (int off = 1; off < 256; off <<= 1) {
            int t = (threadIdx.x >= off) ? s[threadIdx.x - off] : 0;
            __syncthreads();
            s[threadIdx.x] += t;
            __syncthreads();
        }
        int c = carry;
        if (i < n) a[i] = s[threadIdx.x] - v + c;
        __syncthreads();
        if (threadIdx.x == 0) carry = c + s[255];
        __syncthreads();
    }
}

__global__ void k_scan3(int* __restrict__ out, const int* __restrict__ bscan, int n) {
    int i = blockIdx.x * 256 + threadIdx.x;
    if (i < n) out[i] += bscan[blockIdx.x];
}

// fused post-scan: [0,196) invsqrt | [196,3321) atomic-free fill | [3321,5470) prescale xs
__global__ void k_post_scan(const int* __restrict__ ei, const int* __restrict__ ecsbuf,
                            const int* __restrict__ rank, const int* __restrict__ prefix,
                            const int* __restrict__ deg_out, const float* __restrict__ x,
                            float* __restrict__ inv_out, float* __restrict__ inv_in,
                            int* __restrict__ src_sorted, float* __restrict__ xs) {
    int bx = blockIdx.x;
    if (bx < 196) {
        int n = bx * 256 + threadIdx.x;
        if (n >= N_NODES) return;
        int di = ecsbuf[n + 2] - ecsbuf[n + 1];
        int a = deg_out[n]; if (a < 1) a = 1;
        if (di < 1) di = 1;
        inv_out[n] = 1.0f / sqrtf((float)a);
        inv_in[n]  = 1.0f / sqrtf((float)di);
    } else if (bx < 3321) {
        int e = (bx - 196) * 256 + threadIdx.x;
        if (e < N_EDGES) {
            int d = ei[N_EDGES + e];
            int rc = rank[e];
            int c = rc & 31, r = rc >> 5;
            src_sorted[ecsbuf[1 + d] + prefix[c * NPAD + d] + r] = ei[e];
        }
    } else {
        int idx = (bx - 3321) * 256 + threadIdx.x;   // n*11 + f2
        if (idx >= N_NODES * 11) return;
        int n = idx / 11;
        int f2 = idx - n * 11;
        int a = deg_out[n]; if (a < 1) a = 1;
        float sc = 1.0f / sqrtf((float)a);
        float2 v = *(const float2*)&x[n * 22 + f2 * 2];
        v.x *= sc; v.y *= sc;
        *(float2*)&xs[n * 22 + f2 * 2] = v;
    }
}

// ---------------- aggregation ----------------

// layer 0: gather pre-scaled xs (width 22), *inv_in, -> fp16 A (K pad 32).
__global__ void k_agg22(const float* __restrict__ xs,
                        const int* __restrict__ ecsbuf, const int* __restrict__ srcs,
                        const float* __restrict__ inv_in, _Float16* __restrict__ A) {
    int idx = blockIdx.x * 256 + threadIdx.x;
    int n = idx >> 4, f2 = idx & 15;
    if (n >= N_NODES) return;
    float ax = 0.f, ay = 0.f;
    if (f2 <= 10) {
        const float2* xb = (const float2*)(xs) + f2;
        int e = ecsbuf[n + 1], end = ecsbuf[n + 2];
        for (; e + 3 < end; e += 4) {
            int s0 = srcs[e], s1 = srcs[e + 1], s2 = srcs[e + 2], s3 = srcs[e + 3];
            float2 v0 = xb[s0 * 11], v1 = xb[s1 * 11];
            float2 v2 = xb[s2 * 11], v3 = xb[s3 * 11];
            ax += (v0.x + v1.x) + (v2.x + v3.x);
            ay += (v0.y + v1.y) + (v2.y + v3.y);
        }
        for (; e < end; ++e) {
            float2 v0 = xb[srcs[e] * 11];
            ax += v0.x;
            ay += v0.y;
        }
        float si = inv_in[n];
        ax *= si; ay *= si;
    }
    half2_t h2 = {(_Float16)ax, (_Float16)ay};
    *(half2_t*)&A[n * 32 + f2 * 2] = h2;
}

// width-220 gather (h stored fp16, row = 224 halfs = 448 B = 4 sectors) + *inv_in
// -> fp16 A (single rounding).  One node per 64-lane group; lanes 0..54 own 4
// features (8 B half4 loads); 8 loads in flight; fp32 accumulation.
__global__ __launch_bounds__(256) void k_agg220(const _Float16* __restrict__ h,
                                                const int* __restrict__ ecsbuf,
                                                const int* __restrict__ srcs,
                                                const float* __restrict__ inv_in,
                                                _Float16* __restrict__ A) {
    int lane = threadIdx.x & 63;
    int n = blockIdx.x * 4 + (threadIdx.x >> 6);
    if (n >= N_NODES || lane >= 56) return;   // no barriers; early-exit safe
    size_t ob = (size_t)n * 224 + lane * 4;
    if (lane == 55) {                          // K-pad columns 220..223 = 0
        half4 z = {(_Float16)0.f, (_Float16)0.f, (_Float16)0.f, (_Float16)0.f};
        *(half4*)&A[ob] = z;
        return;
    }
    int f4 = lane * 4;
    const _Float16* hb = h + f4;
    int e = ecsbuf[n + 1], end = ecsbuf[n + 2];
    float4 a0 = {0,0,0,0}, a1 = {0,0,0,0}, a2 = {0,0,0,0}, a3 = {0,0,0,0};
    for (; e + 7 < end; e += 8) {
        int s0 = srcs[e],     s1 = srcs[e + 1], s2 = srcs[e + 2], s3 = srcs[e + 3];
        int s4 = srcs[e + 4], s5 = srcs[e + 5], s6 = srcs[e + 6], s7 = srcs[e + 7];
        half4 v0 = *(const half4*)(hb + (size_t)s0 * HSTR);
        half4 v1 = *(const half4*)(hb + (size_t)s1 * HSTR);
        half4 v2 = *(const half4*)(hb + (size_t)s2 * HSTR);
        half4 v3 = *(const half4*)(hb + (size_t)s3 * HSTR);
        half4 v4 = *(const half4*)(hb + (size_t)s4 * HSTR);
        half4 v5 = *(const half4*)(hb + (size_t)s5 * HSTR);
        half4 v6 = *(const half4*)(hb + (size_t)s6 * HSTR);
        half4 v7 = *(const half4*)(hb + (size_t)s7 * HSTR);
        a0.x += (float)v0.x; a0.y += (float)v0.y; a0.z += (float)v0.z; a0.w += (float)v0.w;
        a1.x += (float)v1.x; a1.y += (float)v1.y; a1.z += (float)v1.z; a1.w += (float)v1.w;
        a2.x += (float)v2.x; a2.y += (float)v2.y; a2.z += (float)v2.z; a2.w += (float)v2.w;
        a3.x += (float)v3.x; a3.y += (float)v3.y; a3.z += (float)v3.z; a3.w += (float)v3.w;
        a0.x += (float)v4.x; a0.y += (float)v4.y; a0.z += (float)v4.z; a0.w += (float)v4.w;
        a1.x += (float)v5.x; a1.y += (float)v5.y; a1.z += (float)v5.z; a1.w += (float)v5.w;
        a2.x += (float)v6.x; a2.y += (float)v6.y; a2.z += (float)v6.z; a2.w += (float)v6.w;
        a3.x += (float)v7.x; a3.y += (float)v7.y; a3.z += (float)v7.z; a3.w += (float)v7.w;
    }
    for (; e + 3 < end; e += 4) {
        int s0 = srcs[e], s1 = srcs[e + 1], s2 = srcs[e + 2], s3 = srcs[e + 3];
        half4 v0 = *(const half4*)(hb + (size_t)s0 * HSTR);
        half4 v1 = *(const half4*)(hb + (size_t)s1 * HSTR);
        half4 v2 = *(const half4*)(hb + (size_t)s2 * HSTR);
        half4 v3 = *(const half4*)(hb + (size_t)s3 * HSTR);
        a0.x += (float)v0.x; a0.y += (float)v0.y; a0.z += (float)v0.z; a0.w += (float)v0.w;
        a1.x += (float)v1.x; a1.y += (float)v1.y; a1.z += (float)v1.z; a1.w += (float)v1.w;
        a2.x += (float)v2.x; a2.y += (float)v2.y; a2.z += (float)v2.z; a2.w += (float)v2.w;
        a3.x += (float)v3.x; a3.y += (float)v3.y; a3.z += (float)v3.z; a3.w += (float)v3.w;
    }
    for (; e < end; ++e) {
        half4 v = *(const half4*)(hb + (size_t)srcs[e] * HSTR);
        a0.x += (float)v.x; a0.y += (float)v.y; a0.z += (float)v.z; a0.w += (float)v.w;
    }
    float sc = inv_in[n];
    half4 o;
    o.x = (_Float16)(((a0.x + a1.x) + (a2.x + a3.x)) * sc);
    o.y = (_Float16)(((a0.y + a1.y) + (a2.y + a3.y)) * sc);
    o.z = (_Float16)(((a0.z + a1.z) + (a2.z + a3.z)) * sc);
    o.w = (_Float16)(((a0.w + a1.w) + (a2.w + a3.w)) * sc);
    *(half4*)&A[ob] = o;
}

// layer 3: gather tmp10 halves (width 10 x 2, 4 MB -> L2-resident), *inv_in + bias
__global__ void k_agg10_epi(const float* __restrict__ tmp, const int* __restrict__ ecsbuf,
                            const int* __restrict__ srcs, const float* __restrict__ inv_in,
                            const float* __restrict__ bias, float* __restrict__ out) {
    int idx = blockIdx.x * 256 + threadIdx.x;
    if (idx >= N_NODES * 5) return;
    int n = idx / 5;
    int f2 = idx - n * 5;
    const float2* tb0 = (const float2*)(tmp) + f2;
    const float2* tb1 = (const float2*)(tmp + (size_t)NPAD * 10) + f2;
    float ax = 0.f, ay = 0.f;
    int e = ecsbuf[n + 1], end = ecsbuf[n + 2];
    for (; e + 1 < end; e += 2) {
        float2 u0 = tb0[srcs[e] * 5],     w0 = tb1[srcs[e] * 5];
        float2 u1 = tb0[srcs[e + 1] * 5], w1 = tb1[srcs[e + 1] * 5];
        ax += (u0.x + w0.x) + (u1.x + w1.x);
        ay += (u0.y + w0.y) + (u1.y + w1.y);
    }
    if (e < end) {
        float2 u0 = tb0[srcs[e] * 5], w0 = tb1[srcs[e] * 5];
        ax += u0.x + w0.x;
        ay += u0.y + w0.y;
    }
    float si = inv_in[n];
    float2 o;
    o.x = ax * si + bias[f2 * 2];
    o.y = ay * si + bias[f2 * 2 + 1];
    *(float2*)&out[n * 10 + f2 * 2] = o;
}

// ---------------- f16 MFMA GEMM: A fp16, W split-fp16, pinned batched loads -
// Per ks: A + all 14 B fragments loaded, then asm-volatile liveness pins force
// them resident BEFORE the MFMA cluster (r16: defeats the scheduler's
// load-sinking that kept VGPR=64 / ~3 loads in flight through r13-r15).
// FUSE_W3 epilogue in two 2-row chunks. Wave = 16 rows x 112 cols; block =
// 4 waves; grid 1568; (256,4) cap 128 VGPR. XCD-aligned row mapping kept.
template <int KSTEPS, int LDA, bool FUSE_W3>
__global__ __launch_bounds__(256, 4) void k_gemm_mfma(const _Float16* __restrict__ A,
                                                      const _Float16* __restrict__ WT_hi,
                                                      const _Float16* __restrict__ WT_lo,
                                                      const float* __restrict__ bias,
                                                      const float* __restrict__ post,
                                                      _Float16* __restrict__ out,
                                                      const float* __restrict__ W3,
                                                      float* __restrict__ tmp) {
    constexpr bool SWZ = (LDA == 224);
    int tid = threadIdx.x;
    int l = tid & 63, w = tid >> 6;
    int lrow = l & 15, q = l >> 4;
    int bid = blockIdx.x;

    int ch, s = 0, v = 0, rt = 0;
    if constexpr (SWZ) {
        s = bid & 7;
        int u = bid >> 3;
        ch = u & 1;
        v = u >> 1;                 // [0,98)
    } else {
        ch = bid & 1;
        rt = (bid >> 1) * 64 + w * 16;
    }
    int cb = ch * 112;

    // logical tile row i (0..15) -> physical A/out row
    auto prow = [&](int i) -> int {
        if constexpr (SWZ) return 4 * s + 512 * v + 32 * (4 * w + (i >> 2)) + (i & 3);
        else return rt + i;
    };

    int arow = prow(lrow);
    const _Float16* pa  = A + (size_t)arow * LDA + q * 8;
    const _Float16* pbh = WT_hi + (size_t)(cb + lrow) * LDA + q * 8;
    const _Float16* pbl = WT_lo + (size_t)(cb + lrow) * LDA + q * 8;

    f32x4 acc[7];
#pragma unroll
    for (int ct = 0; ct < 7; ++ct) acc[ct] = (f32x4){0.f, 0.f, 0.f, 0.f};

#pragma unroll
    for (int ks = 0; ks < KSTEPS; ++ks) {
        int k0 = ks * 32;
        // issue all 15 loads of this ks...
        half8 a = *(const half8*)(const void*)(pa + k0);
        half8 bh[7], bl[7];
#pragma unroll
        for (int ct = 0; ct < 7; ++ct) {
            size_t boff = (size_t)(ct * 16) * LDA + k0;
            bh[ct] = *(const half8*)(const void*)(pbh + boff);
            bl[ct] = *(const half8*)(const void*)(pbl + boff);
        }
        // ...and PIN them live so the scheduler can't sink them back to the
        // MFMAs (volatile asm is not crossed; forces 14 loads in flight).
        asm volatile("" :: "v"(a));
#pragma unroll
        for (int ct = 0; ct < 7; ++ct)
            asm volatile("" :: "v"(bh[ct]), "v"(bl[ct]));
#pragma unroll
        for (int ct = 0; ct < 7; ++ct) {
            acc[ct] = mfma16f(a, bh[ct], acc[ct]);
            acc[ct] = mfma16f(a, bl[ct], acc[ct]);
        }
    }

    float pv[4];
#pragma unroll
    for (int r = 0; r < 4; ++r) {
        int r0 = prow(q * 4 + r);
        pv[r] = (r0 < N_NODES) ? post[r0] : 0.f;
    }

    if (!FUSE_W3) {
#pragma unroll
        for (int ct = 0; ct < 7; ++ct) {
            int col = cb + ct * 16 + lrow;
            if (col >= 220) continue;
            float bv = bias[col];
#pragma unroll
            for (int r = 0; r < 4; ++r) {
                int r0 = prow(q * 4 + r);
                if (r0 < N_NODES)
                    out[(size_t)r0 * HSTR + col] = (_Float16)(pv[r] * fast_tanh(acc[ct][r] + bv));
            }
        }
    } else {
        // two 2-row chunks: epilogue register peak = p[2][10] + w3v + acc
#pragma unroll
        for (int rc = 0; rc < 2; ++rc) {
            float p[2][10];
#pragma unroll
            for (int r2 = 0; r2 < 2; ++r2)
#pragma unroll
                for (int j = 0; j < 10; ++j) p[r2][j] = 0.f;
#pragma unroll
            for (int ct = 0; ct < 7; ++ct) {
                int col = cb + ct * 16 + lrow;
                bool cok = col < 220;
                float bv = cok ? bias[col] : 0.f;
                float w3v[10];
                if (cok) {
                    const float2* wp = (const float2*)&W3[col * 10];
#pragma unroll
                    for (int j2 = 0; j2 < 5; ++j2) {
                        float2 t = wp[j2];
                        w3v[2 * j2] = t.x;
                        w3v[2 * j2 + 1] = t.y;
                    }
                } else {
#pragma unroll
                    for (int j = 0; j < 10; ++j) w3v[j] = 0.f;
                }
#pragma unroll
                for (int r2 = 0; r2 < 2; ++r2) {
                    int r = rc * 2 + r2;
                    float h2 = pv[r] * fast_tanh(acc[ct][r] + bv);
#pragma unroll
                    for (int j = 0; j < 10; ++j) p[r2][j] += h2 * w3v[j];
                }
            }
            // reduce over the 16 lanes (same q) sharing each row
#pragma unroll
            for (int r2 = 0; r2 < 2; ++r2)
#pragma unroll
                for (int j = 0; j < 10; ++j) {
                    float vv = p[r2][j];
                    vv += __shfl_xor(vv, 1, 64);
                    vv += __shfl_xor(vv, 2, 64);
                    vv += __shfl_xor(vv, 4, 64);
                    vv += __shfl_xor(vv, 8, 64);
                    p[r2][j] = vv;
                }
            if (lrow == 0) {
#pragma unroll
                for (int r2 = 0; r2 < 2; ++r2) {
                    int row = prow(q * 4 + rc * 2 + r2);
                    if (row < N_NODES) {
                        float* tp = tmp + ((size_t)ch * NPAD + row) * 10;
#pragma unroll
                        for (int j2 = 0; j2 < 5; ++j2) {
                            float2 o = {p[r2][2 * j2], p[r2][2 * j2 + 1]};
                            *(float2*)&tp[2 * j2] = o;
                        }
                    }
                }
            }
        }
    }
}

// ---------------- launch ----------------

extern "C" void kernel_launch(void* const* d_in, const int* in_sizes, int n_in,
                              void* d_out, int out_size, void* d_ws, size_t ws_size,
                              hipStream_t stream) {
    const float* x  = (const float*)d_in[0];
    const float* W0 = (const float*)d_in[1];
    const float* b0 = (const float*)d_in[2];
    const float* W1 = (const float*)d_in[3];
    const float* b1 = (const float*)d_in[4];
    const float* W2 = (const float*)d_in[5];
    const float* b2 = (const float*)d_in[6];
    const float* W3 = (const float*)d_in[7];
    const float* b3 = (const float*)d_in[8];
    const int*   ei = (const int*)d_in[9];
    float* out = (float*)d_out;

    int* ws = (int*)d_ws;
    // word offsets (wt buffers = fp16 splits)
    int* ecsbuf     = ws + 0;               // 50432 (50178 used; [0]=0)
    int* deg_out    = ws + 50432;           // 50176
    int* bsumA      = ws + 100608;          // 256 (196 used)
    float* inv_out  = (float*)(ws + 100864);
    float* inv_in   = (float*)(ws + 151040);
    int* src_sorted = ws + 201216;          // 800000
    _Float16* wt0h = (_Float16*)(ws + 1001216);   // 3584 w
    _Float16* wt0l = (_Float16*)(ws + 1004800);   // 3584 w
    _Float16* wt1h = (_Float16*)(ws + 1008384);   // 25088 w
    _Float16* wt1l = (_Float16*)(ws + 1033472);   // 25088 w
    _Float16* wt2h = (_Float16*)(ws + 1058560);   // 25088 w
    _Float16* wt2l = (_Float16*)(ws + 1083648);   // 25088 w
    _Float16* Abuf = (_Float16*)(ws + 1108736);   // NPAD*224 halfs = 5619712 w
    int* scratch   = ws + 6728448;                // 5619712 w
    _Float16* hbuf = (_Float16*)(ws + 12348160);  // 50000*224 halfs = 2800000 w
    float* tmp10 = (float*)(ws + 17948160); // 2*NPAD*10 = 1003520 w -> end 18951680
    // aliases in regions not yet live at CSR-build time:
    int* rank     = (int*)Abuf;                   // Abuf words [0, 800000)
    int* cnt_part = scratch;                      // [0, 1605632)
    int* deg_part = scratch + NCHK * NPAD;        // [1605632, 3211264)
    float* xs = (float*)(ws + 1108736 + 3000000); // Abuf words [3000000,4100000): dead by layer-1 agg

    // CSR build: zero global atomics (LDS hist jobs fully overwrite partials)
    k_build<<<676, 256, 0, stream>>>(ei, deg_part, cnt_part, rank,
                                     W0, W1, W2, wt0h, wt0l, wt1h, wt1l, wt2h, wt2l);
    k_sum32<<<196, 256, 0, stream>>>(cnt_part, deg_part, ecsbuf, deg_out);
    k_scan1<<<196, 256, 0, stream>>>(ecsbuf + 1, ecsbuf + 1, bsumA, NPAD);
    k_scan_mid<<<1, 256, 0, stream>>>(bsumA, 196);
    k_scan3<<<196, 256, 0, stream>>>(ecsbuf + 1, bsumA, NPAD);
    k_post_scan<<<5470, 256, 0, stream>>>(ei, ecsbuf, rank, cnt_part, deg_out, x,
                                          inv_out, inv_in, src_sorted, xs);

    int gemm_grid = (NPAD / 64) * 2;         // 1568 (both mappings)
    int agg_grid  = (N_NODES + 3) / 4;       // 12500

    // ---- layer 0
    k_agg22<<<(N_NODES * 16 + 255) / 256, 256, 0, stream>>>(
        xs, ecsbuf, src_sorted, inv_in, Abuf);
    k_gemm_mfma<1, 32, false><<<gemm_grid, 256, 0, stream>>>(
        Abuf, wt0h, wt0l, b0, inv_out, hbuf, nullptr, nullptr);

    // ---- layer 1
    k_agg220<<<agg_grid, 256, 0, stream>>>(hbuf, ecsbuf, src_sorted, inv_in, Abuf);
    k_gemm_mfma<7, 224, false><<<gemm_grid, 256, 0, stream>>>(
        Abuf, wt1h, wt1l, b1, inv_out, hbuf, nullptr, nullptr);

    // ---- layer 2 (+ fused W3 projection; h2 never materialized)
    k_agg220<<<agg_grid, 256, 0, stream>>>(hbuf, ecsbuf, src_sorted, inv_in, Abuf);
    k_gemm_mfma<7, 224, true><<<gemm_grid, 256, 0, stream>>>(
        Abuf, wt2h, wt2l, b2, inv_out, nullptr, W3, tmp10);

    // ---- layer 3
    k_agg10_epi<<<(N_NODES * 5 + 255) / 256, 256, 0, stream>>>(
        tmp10, ecsbuf, src_sorted, inv_in, b3, out);
}

// Round 17
// 379.324 us; speedup vs baseline: 1.1128x; 1.1128x over previous
//
#include <hip/hip_runtime.h>
#include <math.h>

#define N_NODES 50000
#define N_EDGES 800000
#define NPAD 50176
#define HSTR 224   // hbuf row stride in HALFS: 448 B = exactly 4 x 128B sectors per row fetch
#define RBIN 12544 // bins per histogram range (NPAD/4), 49 KB LDS as int
#define NCHK 32    // edge chunks; chunk = 25000 edges
// ecsbuf (NPAD+2 ints): after k_sum32, ecsbuf[1+d] = total in-degree count;
// after scans, ecsbuf[1+d] = start(d). Readers: start(n)=ecsbuf[n+1], end=ecsbuf[n+2].
// CSR build: ZERO global atomics (r7/r11). GEMM numerics (r12): A fp16,
// W split-fp16, f16 MFMA: D = A*(Whi+Wlo); absmax pinned at 1.5e-5.
// GEMM schedule history: r13/r15/r16 all failed to force >3 global loads in
// flight (compiler pins VGPR=64, sinks loads to consumers). r17: stop fighting
// the scheduler — stage B in LDS per block. Col-half tile = 112x32x(hi+lo)
// = 16.1 KB/buf, dbuf 32.3 KB -> 5 blocks/CU (vs r1's 64.5KB/1.5 blocks
// occupancy cliff). B L2 traffic /4; ds_read gets fine-grained lgkmcnt.

typedef __attribute__((ext_vector_type(8))) _Float16 half8;
typedef __attribute__((ext_vector_type(4))) float f32x4;
typedef __attribute__((ext_vector_type(4))) _Float16 half4;
typedef __attribute__((ext_vector_type(2))) _Float16 half2_t;

// ---------------- helpers ----------------

__device__ __forceinline__ float fast_tanh(float x) {
    float e = __expf(2.0f * x);
    float r = __builtin_amdgcn_rcpf(e + 1.0f);
    return 1.0f - 2.0f * r;
}

__device__ __forceinline__ f32x4 mfma16f(half8 a, half8 b, f32x4 c) {
    return __builtin_amdgcn_mfma_f32_16x16x32_f16(a, b, c, 0, 0, 0);
}

// split W to fp16 hi + fp16 lo (hi = RNE(v); lo = RNE(v - hi))
__device__ __forceinline__ void wsplit_one(const float* __restrict__ W, int KIN, int LDA,
                                           _Float16* __restrict__ WT_hi,
                                           _Float16* __restrict__ WT_lo, int idx) {
    int n = idx / LDA;
    int k = idx - n * LDA;
    float v = (n < 220 && k < KIN) ? W[k * 220 + n] : 0.f;
    _Float16 hi = (_Float16)v;
    _Float16 lo = (_Float16)(v - (float)hi);
    WT_hi[idx] = hi;
    WT_lo[idx] = lo;
}

// ---------------- CSR build (zero global atomics) ----------------

// partitioned launch:
// [0,128)    dst rank job: rng = bx>>5, chk = bx&31 (4 ranges x 32 chunks)
// [128,256)  src hist job: same decomposition
// [256,284)  wsplit W0 | [284,480) W1 | [480,676) W2
__global__ void k_build(const int* __restrict__ ei, int* __restrict__ deg_part,
                        int* __restrict__ cnt_part, int* __restrict__ rank,
                        const float* __restrict__ W0, const float* __restrict__ W1,
                        const float* __restrict__ W2,
                        _Float16* __restrict__ wt0h, _Float16* __restrict__ wt0l,
                        _Float16* __restrict__ wt1h, _Float16* __restrict__ wt1l,
                        _Float16* __restrict__ wt2h, _Float16* __restrict__ wt2l) {
    __shared__ int hb[RBIN];   // 49 KB -> 3 blocks/CU
    int bx = blockIdx.x;
    if (bx < 128) {
        int rng = bx >> 5, chk = bx & 31;
        int lo = rng * RBIN;
        for (int i = threadIdx.x; i < RBIN; i += 256) hb[i] = 0;
        __syncthreads();
        int ebeg = chk * 25000, eend = ebeg + 25000;
        for (int e = ebeg + threadIdx.x; e < eend; e += 256) {
            int d = ei[N_EDGES + e];
            unsigned idx = (unsigned)(d - lo);
            if (idx < (unsigned)RBIN) {
                int lr = atomicAdd(&hb[idx], 1);     // LDS returning add
                rank[e] = (lr << 5) | chk;
            }
        }
        __syncthreads();
        for (int i = threadIdx.x; i < RBIN; i += 256)
            cnt_part[chk * NPAD + lo + i] = hb[i];
    } else if (bx < 256) {
        int b2 = bx - 128;
        int rng = b2 >> 5, chk = b2 & 31;
        int lo = rng * RBIN;
        for (int i = threadIdx.x; i < RBIN; i += 256) hb[i] = 0;
        __syncthreads();
        int ebeg = chk * 25000, eend = ebeg + 25000;
        for (int e = ebeg + threadIdx.x; e < eend; e += 256) {
            int s = ei[e];
            unsigned idx = (unsigned)(s - lo);
            if (idx < (unsigned)RBIN) atomicAdd(&hb[idx], 1);
        }
        __syncthreads();
        for (int i = threadIdx.x; i < RBIN; i += 256)
            deg_part[chk * NPAD + lo + i] = hb[i];
    } else if (bx < 284) {
        int idx = (bx - 256) * 256 + threadIdx.x;           // 224*32 = 7168
        if (idx < 224 * 32) wsplit_one(W0, 22, 32, wt0h, wt0l, idx);
    } else if (bx < 480) {
        int idx = (bx - 284) * 256 + threadIdx.x;           // 224*224 = 50176
        wsplit_one(W1, 220, 224, wt1h, wt1l, idx);
    } else {
        int idx = (bx - 480) * 256 + threadIdx.x;
        wsplit_one(W2, 220, 224, wt2h, wt2l, idx);
    }
}

// fold 32 chunk-partials: cnt_part -> in-place exclusive per-bin prefix,
// ecsbuf[1+d] = total in-degree, deg_out[d] = total out-degree.
__global__ void k_sum32(int* __restrict__ cnt_part, const int* __restrict__ deg_part,
                        int* __restrict__ ecsbuf, int* __restrict__ deg_out) {
    int d = blockIdx.x * 256 + threadIdx.x;
    if (d >= NPAD) return;
    int s = 0;
#pragma unroll
    for (int c = 0; c < NCHK; ++c) {
        int v = cnt_part[c * NPAD + d];
        cnt_part[c * NPAD + d] = s;
        s += v;
    }
    ecsbuf[1 + d] = s;
    if (d == 0) ecsbuf[0] = 0;
    int t = 0;
#pragma unroll
    for (int c = 0; c < NCHK; ++c) t += deg_part[c * NPAD + d];
    deg_out[d] = t;
}

__global__ void k_scan1(const int* __restrict__ in, int* __restrict__ out,
                        int* __restrict__ bsum, int n) {
    __shared__ int s[256];
    int i = blockIdx.x * 256 + threadIdx.x;
    int v = (i < n) ? in[i] : 0;
    s[threadIdx.x] = v;
    __syncthreads();
    for (int off = 1; off < 256; off <<= 1) {
        int t = (threadIdx.x >= off) ? s[threadIdx.x - off] : 0;
        __syncthreads();
        s[threadIdx.x] += t;
        __syncthreads();
    }
    if (i < n) out[i] = s[threadIdx.x] - v;   // exclusive
    if (threadIdx.x == 255 && bsum) bsum[blockIdx.x] = s[255];
}

__global__ void k_scan_mid(int* __restrict__ a, int n) {
    __shared__ int s[256];
    __shared__ int carry;
    if (threadIdx.x == 0) carry = 0;
    for (int base = 0; base < n; base += 256) {
        int i = base + threadIdx.x;
        int v = (i < n) ? a[i] : 0;
        s[threadIdx.x] = v;
        __syncthreads();
        for (int off = 1; off < 256; off <<= 1) {
            int t = (threadIdx.x >= off) ? s[threadIdx.x - off] : 0;
            __syncthreads();
            s[threadIdx.x] += t;
            __syncthreads();
        }
        int c = carry;
        if (i < n) a[i] = s[threadIdx.x] - v + c;
        __syncthreads();
        if (threadIdx.x == 0) carry = c + s[255];
        __syncthreads();
    }
}

__global__ void k_scan3(int* __restrict__ out, const int* __restrict__ bscan, int n) {
    int i = blockIdx.x * 256 + threadIdx.x;
    if (i < n) out[i] += bscan[blockIdx.x];
}

// fused post-scan: [0,196) invsqrt | [196,3321) atomic-free fill | [3321,5470) prescale xs
__global__ void k_post_scan(const int* __restrict__ ei, const int* __restrict__ ecsbuf,
                            const int* __restrict__ rank, const int* __restrict__ prefix,
                            const int* __restrict__ deg_out, const float* __restrict__ x,
                            float* __restrict__ inv_out, float* __restrict__ inv_in,
                            int* __restrict__ src_sorted, float* __restrict__ xs) {
    int bx = blockIdx.x;
    if (bx < 196) {
        int n = bx * 256 + threadIdx.x;
        if (n >= N_NODES) return;
        int di = ecsbuf[n + 2] - ecsbuf[n + 1];
        int a = deg_out[n]; if (a < 1) a = 1;
        if (di < 1) di = 1;
        inv_out[n] = 1.0f / sqrtf((float)a);
        inv_in[n]  = 1.0f / sqrtf((float)di);
    } else if (bx < 3321) {
        int e = (bx - 196) * 256 + threadIdx.x;
        if (e < N_EDGES) {
            int d = ei[N_EDGES + e];
            int rc = rank[e];
            int c = rc & 31, r = rc >> 5;
            src_sorted[ecsbuf[1 + d] + prefix[c * NPAD + d] + r] = ei[e];
        }
    } else {
        int idx = (bx - 3321) * 256 + threadIdx.x;   // n*11 + f2
        if (idx >= N_NODES * 11) return;
        int n = idx / 11;
        int f2 = idx - n * 11;
        int a = deg_out[n]; if (a < 1) a = 1;
        float sc = 1.0f / sqrtf((float)a);
        float2 v = *(const float2*)&x[n * 22 + f2 * 2];
        v.x *= sc; v.y *= sc;
        *(float2*)&xs[n * 22 + f2 * 2] = v;
    }
}

// ---------------- aggregation ----------------

// layer 0: gather pre-scaled xs (width 22), *inv_in, -> fp16 A (K pad 32).
__global__ void k_agg22(const float* __restrict__ xs,
                        const int* __restrict__ ecsbuf, const int* __restrict__ srcs,
                        const float* __restrict__ inv_in, _Float16* __restrict__ A) {
    int idx = blockIdx.x * 256 + threadIdx.x;
    int n = idx >> 4, f2 = idx & 15;
    if (n >= N_NODES) return;
    float ax = 0.f, ay = 0.f;
    if (f2 <= 10) {
        const float2* xb = (const float2*)(xs) + f2;
        int e = ecsbuf[n + 1], end = ecsbuf[n + 2];
        for (; e + 3 < end; e += 4) {
            int s0 = srcs[e], s1 = srcs[e + 1], s2 = srcs[e + 2], s3 = srcs[e + 3];
            float2 v0 = xb[s0 * 11], v1 = xb[s1 * 11];
            float2 v2 = xb[s2 * 11], v3 = xb[s3 * 11];
            ax += (v0.x + v1.x) + (v2.x + v3.x);
            ay += (v0.y + v1.y) + (v2.y + v3.y);
        }
        for (; e < end; ++e) {
            float2 v0 = xb[srcs[e] * 11];
            ax += v0.x;
            ay += v0.y;
        }
        float si = inv_in[n];
        ax *= si; ay *= si;
    }
    half2_t h2 = {(_Float16)ax, (_Float16)ay};
    *(half2_t*)&A[n * 32 + f2 * 2] = h2;
}

// width-220 gather (h stored fp16, row = 224 halfs = 448 B = 4 sectors) + *inv_in
// -> fp16 A (single rounding).  One node per 64-lane group; lanes 0..54 own 4
// features (8 B half4 loads); 8 loads in flight; fp32 accumulation.
__global__ __launch_bounds__(256) void k_agg220(const _Float16* __restrict__ h,
                                                const int* __restrict__ ecsbuf,
                                                const int* __restrict__ srcs,
                                                const float* __restrict__ inv_in,
                                                _Float16* __restrict__ A) {
    int lane = threadIdx.x & 63;
    int n = blockIdx.x * 4 + (threadIdx.x >> 6);
    if (n >= N_NODES || lane >= 56) return;   // no barriers; early-exit safe
    size_t ob = (size_t)n * 224 + lane * 4;
    if (lane == 55) {                          // K-pad columns 220..223 = 0
        half4 z = {(_Float16)0.f, (_Float16)0.f, (_Float16)0.f, (_Float16)0.f};
        *(half4*)&A[ob] = z;
        return;
    }
    int f4 = lane * 4;
    const _Float16* hb = h + f4;
    int e = ecsbuf[n + 1], end = ecsbuf[n + 2];
    float4 a0 = {0,0,0,0}, a1 = {0,0,0,0}, a2 = {0,0,0,0}, a3 = {0,0,0,0};
    for (; e + 7 < end; e += 8) {
        int s0 = srcs[e],     s1 = srcs[e + 1], s2 = srcs[e + 2], s3 = srcs[e + 3];
        int s4 = srcs[e + 4], s5 = srcs[e + 5], s6 = srcs[e + 6], s7 = srcs[e + 7];
        half4 v0 = *(const half4*)(hb + (size_t)s0 * HSTR);
        half4 v1 = *(const half4*)(hb + (size_t)s1 * HSTR);
        half4 v2 = *(const half4*)(hb + (size_t)s2 * HSTR);
        half4 v3 = *(const half4*)(hb + (size_t)s3 * HSTR);
        half4 v4 = *(const half4*)(hb + (size_t)s4 * HSTR);
        half4 v5 = *(const half4*)(hb + (size_t)s5 * HSTR);
        half4 v6 = *(const half4*)(hb + (size_t)s6 * HSTR);
        half4 v7 = *(const half4*)(hb + (size_t)s7 * HSTR);
        a0.x += (float)v0.x; a0.y += (float)v0.y; a0.z += (float)v0.z; a0.w += (float)v0.w;
        a1.x += (float)v1.x; a1.y += (float)v1.y; a1.z += (float)v1.z; a1.w += (float)v1.w;
        a2.x += (float)v2.x; a2.y += (float)v2.y; a2.z += (float)v2.z; a2.w += (float)v2.w;
        a3.x += (float)v3.x; a3.y += (float)v3.y; a3.z += (float)v3.z; a3.w += (float)v3.w;
        a0.x += (float)v4.x; a0.y += (float)v4.y; a0.z += (float)v4.z; a0.w += (float)v4.w;
        a1.x += (float)v5.x; a1.y += (float)v5.y; a1.z += (float)v5.z; a1.w += (float)v5.w;
        a2.x += (float)v6.x; a2.y += (float)v6.y; a2.z += (float)v6.z; a2.w += (float)v6.w;
        a3.x += (float)v7.x; a3.y += (float)v7.y; a3.z += (float)v7.z; a3.w += (float)v7.w;
    }
    for (; e + 3 < end; e += 4) {
        int s0 = srcs[e], s1 = srcs[e + 1], s2 = srcs[e + 2], s3 = srcs[e + 3];
        half4 v0 = *(const half4*)(hb + (size_t)s0 * HSTR);
        half4 v1 = *(const half4*)(hb + (size_t)s1 * HSTR);
        half4 v2 = *(const half4*)(hb + (size_t)s2 * HSTR);
        half4 v3 = *(const half4*)(hb + (size_t)s3 * HSTR);
        a0.x += (float)v0.x; a0.y += (float)v0.y; a0.z += (float)v0.z; a0.w += (float)v0.w;
        a1.x += (float)v1.x; a1.y += (float)v1.y; a1.z += (float)v1.z; a1.w += (float)v1.w;
        a2.x += (float)v2.x; a2.y += (float)v2.y; a2.z += (float)v2.z; a2.w += (float)v2.w;
        a3.x += (float)v3.x; a3.y += (float)v3.y; a3.z += (float)v3.z; a3.w += (float)v3.w;
    }
    for (; e < end; ++e) {
        half4 v = *(const half4*)(hb + (size_t)srcs[e] * HSTR);
        a0.x += (float)v.x; a0.y += (float)v.y; a0.z += (float)v.z; a0.w += (float)v.w;
    }
    float sc = inv_in[n];
    half4 o;
    o.x = (_Float16)(((a0.x + a1.x) + (a2.x + a3.x)) * sc);
    o.y = (_Float16)(((a0.y + a1.y) + (a2.y + a3.y)) * sc);
    o.z = (_Float16)(((a0.z + a1.z) + (a2.z + a3.z)) * sc);
    o.w = (_Float16)(((a0.w + a1.w) + (a2.w + a3.w)) * sc);
    *(half4*)&A[ob] = o;
}

// layer 3: gather tmp10 halves (width 10 x 2, 4 MB -> L2-resident), *inv_in + bias
__global__ void k_agg10_epi(const float* __restrict__ tmp, const int* __restrict__ ecsbuf,
                            const int* __restrict__ srcs, const float* __restrict__ inv_in,
                            const float* __restrict__ bias, float* __restrict__ out) {
    int idx = blockIdx.x * 256 + threadIdx.x;
    if (idx >= N_NODES * 5) return;
    int n = idx / 5;
    int f2 = idx - n * 5;
    const float2* tb0 = (const float2*)(tmp) + f2;
    const float2* tb1 = (const float2*)(tmp + (size_t)NPAD * 10) + f2;
    float ax = 0.f, ay = 0.f;
    int e = ecsbuf[n + 1], end = ecsbuf[n + 2];
    for (; e + 1 < end; e += 2) {
        float2 u0 = tb0[srcs[e] * 5],     w0 = tb1[srcs[e] * 5];
        float2 u1 = tb0[srcs[e + 1] * 5], w1 = tb1[srcs[e + 1] * 5];
        ax += (u0.x + w0.x) + (u1.x + w1.x);
        ay += (u0.y + w0.y) + (u1.y + w1.y);
    }
    if (e < end) {
        float2 u0 = tb0[srcs[e] * 5], w0 = tb1[srcs[e] * 5];
        ax += u0.x + w0.x;
        ay += u0.y + w0.y;
    }
    float si = inv_in[n];
    float2 o;
    o.x = ax * si + bias[f2 * 2];
    o.y = ay * si + bias[f2 * 2 + 1];
    *(float2*)&out[n * 10 + f2 * 2] = o;
}

// ---------------- f16 MFMA GEMM: A fp16, W split-fp16, LDS-staged B ---------
// r17: B K-slice staged in LDS per block, double-buffered.
// Buffer = [112 rows][72 halfs] (hi 0..31 | lo 32..63 | pad 64..71; 144 B row
// stride -> 2 lanes/bank on ds_read_b128 = free). 16.1 KB/buf, 32.3 KB total
// -> 5 blocks/CU (r1's cliff was 64.5 KB -> 1.5 blocks/CU). One barrier/ks:
// iter ks reads buf[ks&1], stages buf[1-(ks&1)]; barrier retires both.
// No early exits -> barriers uniform. Wave = 16 rows x 112 cols; block =
// 4 waves = 64 rows x one col-half; grid 1568; XCD-aligned row mapping kept.
template <int KSTEPS, int LDA, bool FUSE_W3>
__global__ __launch_bounds__(256, 4) void k_gemm_mfma(const _Float16* __restrict__ A,
                                                      const _Float16* __restrict__ WT_hi,
                                                      const _Float16* __restrict__ WT_lo,
                                                      const float* __restrict__ bias,
                                                      const float* __restrict__ post,
                                                      _Float16* __restrict__ out,
                                                      const float* __restrict__ W3,
                                                      float* __restrict__ tmp) {
    __shared__ _Float16 Bs[2][112 * 72];   // 32,256 B

    constexpr bool SWZ = (LDA == 224);
    int tid = threadIdx.x;
    int l = tid & 63, w = tid >> 6;
    int lrow = l & 15, q = l >> 4;
    int bid = blockIdx.x;

    int ch, s = 0, v = 0, rt = 0;
    if constexpr (SWZ) {
        s = bid & 7;
        int u = bid >> 3;
        ch = u & 1;
        v = u >> 1;                 // [0,98)
    } else {
        ch = bid & 1;
        rt = (bid >> 1) * 64 + w * 16;
    }
    int cb = ch * 112;

    // logical tile row i (0..15) -> physical A/out row
    auto prow = [&](int i) -> int {
        if constexpr (SWZ) return 4 * s + 512 * v + 32 * (4 * w + (i >> 2)) + (i & 3);
        else return rt + i;
    };

    int arow = prow(lrow);
    const _Float16* pa = A + (size_t)arow * LDA + q * 8;

    // stage: 112 rows x (32 hi + 32 lo) halfs = 896 8-half chunks; 4/thread.
    // chunk c: row = c>>3, sub = c&7 (sub<4: hi cols (sub)*8; else lo).
    auto stage = [&](int buf, int ks) {
        int k0 = ks * 32;
#pragma unroll
        for (int i = 0; i < 4; ++i) {
            int c = tid + 256 * i;
            if (c < 896) {
                int row = c >> 3, sub = c & 7;
                int kc = (sub & 3) * 8;
                const _Float16* g = (sub < 4 ? WT_hi : WT_lo) + (size_t)(cb + row) * LDA + k0 + kc;
                *(half8*)&Bs[buf][row * 72 + (sub >= 4 ? 32 : 0) + kc] = *(const half8*)(const void*)g;
            }
        }
    };

    stage(0, 0);
    __syncthreads();

    f32x4 acc[7];
#pragma unroll
    for (int ct = 0; ct < 7; ++ct) acc[ct] = (f32x4){0.f, 0.f, 0.f, 0.f};

    int bro = lrow * 72 + q * 8;   // base read offset within a ct-tile

#pragma unroll
    for (int ks = 0; ks < KSTEPS; ++ks) {
        int cur = ks & 1;
        if (ks + 1 < KSTEPS) stage(1 - cur, ks + 1);

        half8 a = *(const half8*)(const void*)(pa + ks * 32);
#pragma unroll
        for (int ct = 0; ct < 7; ++ct) {
            const _Float16* bp = &Bs[cur][ct * 16 * 72 + bro];
            half8 bh = *(const half8*)(const void*)bp;
            half8 bl = *(const half8*)(const void*)(bp + 32);
            acc[ct] = mfma16f(a, bh, acc[ct]);
            acc[ct] = mfma16f(a, bl, acc[ct]);
        }
        __syncthreads();
    }

    float pv[4];
#pragma unroll
    for (int r = 0; r < 4; ++r) {
        int r0 = prow(q * 4 + r);
        pv[r] = (r0 < N_NODES) ? post[r0] : 0.f;
    }

    if (!FUSE_W3) {
#pragma unroll
        for (int ct = 0; ct < 7; ++ct) {
            int col = cb + ct * 16 + lrow;
            if (col >= 220) continue;
            float bv = bias[col];
#pragma unroll
            for (int r = 0; r < 4; ++r) {
                int r0 = prow(q * 4 + r);
                if (r0 < N_NODES)
                    out[(size_t)r0 * HSTR + col] = (_Float16)(pv[r] * fast_tanh(acc[ct][r] + bv));
            }
        }
    } else {
        float p[4][10];
#pragma unroll
        for (int r = 0; r < 4; ++r)
#pragma unroll
            for (int j = 0; j < 10; ++j) p[r][j] = 0.f;
#pragma unroll
        for (int ct = 0; ct < 7; ++ct) {
            int col = cb + ct * 16 + lrow;
            bool cok = col < 220;
            float bv = cok ? bias[col] : 0.f;
            float w3v[10];
            if (cok) {
                const float2* wp = (const float2*)&W3[col * 10];
#pragma unroll
                for (int j2 = 0; j2 < 5; ++j2) {
                    float2 t = wp[j2];
                    w3v[2 * j2] = t.x;
                    w3v[2 * j2 + 1] = t.y;
                }
            } else {
#pragma unroll
                for (int j = 0; j < 10; ++j) w3v[j] = 0.f;
            }
#pragma unroll
            for (int r = 0; r < 4; ++r) {
                float h2 = pv[r] * fast_tanh(acc[ct][r] + bv);
#pragma unroll
                for (int j = 0; j < 10; ++j) p[r][j] += h2 * w3v[j];
            }
        }
        // reduce over the 16 lanes (same q) sharing each row
#pragma unroll
        for (int r = 0; r < 4; ++r)
#pragma unroll
            for (int j = 0; j < 10; ++j) {
                float vv = p[r][j];
                vv += __shfl_xor(vv, 1, 64);
                vv += __shfl_xor(vv, 2, 64);
                vv += __shfl_xor(vv, 4, 64);
                vv += __shfl_xor(vv, 8, 64);
                p[r][j] = vv;
            }
        if (lrow == 0) {
#pragma unroll
            for (int r = 0; r < 4; ++r) {
                int row = prow(q * 4 + r);
                if (row < N_NODES) {
                    float* tp = tmp + ((size_t)ch * NPAD + row) * 10;
#pragma unroll
                    for (int j2 = 0; j2 < 5; ++j2) {
                        float2 o = {p[r][2 * j2], p[r][2 * j2 + 1]};
                        *(float2*)&tp[2 * j2] = o;
                    }
                }
            }
        }
    }
}

// ---------------- launch ----------------

extern "C" void kernel_launch(void* const* d_in, const int* in_sizes, int n_in,
                              void* d_out, int out_size, void* d_ws, size_t ws_size,
                              hipStream_t stream) {
    const float* x  = (const float*)d_in[0];
    const float* W0 = (const float*)d_in[1];
    const float* b0 = (const float*)d_in[2];
    const float* W1 = (const float*)d_in[3];
    const float* b1 = (const float*)d_in[4];
    const float* W2 = (const float*)d_in[5];
    const float* b2 = (const float*)d_in[6];
    const float* W3 = (const float*)d_in[7];
    const float* b3 = (const float*)d_in[8];
    const int*   ei = (const int*)d_in[9];
    float* out = (float*)d_out;

    int* ws = (int*)d_ws;
    // word offsets (wt buffers = fp16 splits)
    int* ecsbuf     = ws + 0;               // 50432 (50178 used; [0]=0)
    int* deg_out    = ws + 50432;           // 50176
    int* bsumA      = ws + 100608;          // 256 (196 used)
    float* inv_out  = (float*)(ws + 100864);
    float* inv_in   = (float*)(ws + 151040);
    int* src_sorted = ws + 201216;          // 800000
    _Float16* wt0h = (_Float16*)(ws + 1001216);   // 3584 w
    _Float16* wt0l = (_Float16*)(ws + 1004800);   // 3584 w
    _Float16* wt1h = (_Float16*)(ws + 1008384);   // 25088 w
    _Float16* wt1l = (_Float16*)(ws + 1033472);   // 25088 w
    _Float16* wt2h = (_Float16*)(ws + 1058560);   // 25088 w
    _Float16* wt2l = (_Float16*)(ws + 1083648);   // 25088 w
    _Float16* Abuf = (_Float16*)(ws + 1108736);   // NPAD*224 halfs = 5619712 w
    int* scratch   = ws + 6728448;                // 5619712 w
    _Float16* hbuf = (_Float16*)(ws + 12348160);  // 50000*224 halfs = 2800000 w
    float* tmp10 = (float*)(ws + 17948160); // 2*NPAD*10 = 1003520 w -> end 18951680
    // aliases in regions not yet live at CSR-build time:
    int* rank     = (int*)Abuf;                   // Abuf words [0, 800000)
    int* cnt_part = scratch;                      // [0, 1605632)
    int* deg_part = scratch + NCHK * NPAD;        // [1605632, 3211264)
    float* xs = (float*)(ws + 1108736 + 3000000); // Abuf words [3000000,4100000): dead by layer-1 agg

    // CSR build: zero global atomics (LDS hist jobs fully overwrite partials)
    k_build<<<676, 256, 0, stream>>>(ei, deg_part, cnt_part, rank,
                                     W0, W1, W2, wt0h, wt0l, wt1h, wt1l, wt2h, wt2l);
    k_sum32<<<196, 256, 0, stream>>>(cnt_part, deg_part, ecsbuf, deg_out);
    k_scan1<<<196, 256, 0, stream>>>(ecsbuf + 1, ecsbuf + 1, bsumA, NPAD);
    k_scan_mid<<<1, 256, 0, stream>>>(bsumA, 196);
    k_scan3<<<196, 256, 0, stream>>>(ecsbuf + 1, bsumA, NPAD);
    k_post_scan<<<5470, 256, 0, stream>>>(ei, ecsbuf, rank, cnt_part, deg_out, x,
                                          inv_out, inv_in, src_sorted, xs);

    int gemm_grid = (NPAD / 64) * 2;         // 1568 (both mappings)
    int agg_grid  = (N_NODES + 3) / 4;       // 12500

    // ---- layer 0
    k_agg22<<<(N_NODES * 16 + 255) / 256, 256, 0, stream>>>(
        xs, ecsbuf, src_sorted, inv_in, Abuf);
    k_gemm_mfma<1, 32, false><<<gemm_grid, 256, 0, stream>>>(
        Abuf, wt0h, wt0l, b0, inv_out, hbuf, nullptr, nullptr);

    // ---- layer 1
    k_agg220<<<agg_grid, 256, 0, stream>>>(hbuf, ecsbuf, src_sorted, inv_in, Abuf);
    k_gemm_mfma<7, 224, false><<<gemm_grid, 256, 0, stream>>>(
        Abuf, wt1h, wt1l, b1, inv_out, hbuf, nullptr, nullptr);

    // ---- layer 2 (+ fused W3 projection; h2 never materialized)
    k_agg220<<<agg_grid, 256, 0, stream>>>(hbuf, ecsbuf, src_sorted, inv_in, Abuf);
    k_gemm_mfma<7, 224, true><<<gemm_grid, 256, 0, stream>>>(
        Abuf, wt2h, wt2l, b2, inv_out, nullptr, W3, tmp10);

    // ---- layer 3
    k_agg10_epi<<<(N_NODES * 5 + 255) / 256, 256, 0, stream>>>(
        tmp10, ecsbuf, src_sorted, inv_in, b3, out);
}